// Round 6
// baseline (892.267 us; speedup 1.0000x reference)
//
#include <hip/hip_runtime.h>
#include <hip/hip_bf16.h>
#include <math.h>
#include <type_traits>

typedef __hip_bfloat16 bf16;
typedef __attribute__((ext_vector_type(8))) short bf16x8;
typedef __attribute__((ext_vector_type(4))) float f32x4;

#define B_    4
#define H_    128
#define W_    256
#define HW_   32768          // H_*W_
#define CTXC  172
#define NPIX  131072         // B_*HW_
#define RW    258            // W_+2 (halo row width)
#define RH    130            // H_+2
#define IPX   33540          // RW*RH pixels per image (halo incl.)

__device__ __forceinline__ float b2f(bf16 v) { return __bfloat162float(v); }
__device__ __forceinline__ bf16  f2b(float v){ return __float2bfloat16(v); }
__device__ __forceinline__ unsigned short f2bu(float v){ bf16 h = f2b(v); return *(unsigned short*)&h; }
__device__ __forceinline__ float ldv(const float* p){ return *p; }
__device__ __forceinline__ float ldv(const bf16* p) { return b2f(*p); }

// ------------------------------------------------------------- dtype detect --
__global__ void detect_k(const unsigned int* __restrict__ feat_raw,
                         int* __restrict__ flag)
{
    if (threadIdx.x != 0 || blockIdx.x != 0) return;
    int hits = 0;
    for (int i = 0; i < 64; ++i) {
        unsigned int w = feat_raw[i];
        unsigned int e = (w >> 7) & 0xFFu;
        hits += (e >= 0xC0u) ? 1 : 0;
    }
    *flag = (hits > 0) ? 1 : 0;
}

template<typename IT>
__device__ __forceinline__ bool gate_skip(const int* flag)
{
    constexpr bool isf = std::is_same<IT, float>::value;
    return (*flag != 0) != isf;
}

// ---------------------------------------------------- weight fragment shuffle
// GRU conv weights [64][236][3][3] -> B-fragment order, packed at (NTtot,ubase).
// K-order per tap: k 0..191 = ctx channel k (orig ci=64+k; k>=172 zero),
//                  k 192..255 = feat channel (orig ci=k-192).
template<typename IT>
__global__ __launch_bounds__(256) void wfrag_gru(const int* __restrict__ flag,
                                                 const IT* __restrict__ src,
                                                 bf16* __restrict__ dst,
                                                 int NTtot, int ubase)
{
    if (gate_skip<IT>(flag)) return;
    int i = blockIdx.x * 256 + threadIdx.x;
    if (i >= 9*8*4*64*8) return;
    int j    = i & 7;
    int lane = (i >> 3) & 63;
    int u    = (i >> 9) & 3;
    int s    = (i >> 11) & 7;
    int t    = i >> 14;
    int klocal = ((lane >> 4) << 3) + j;
    int co = u * 16 + (lane & 15);
    float v = 0.f;
    if (s < 6) {
        int k = s * 32 + klocal;
        if (k < CTXC) v = ldv(src + ((size_t)co * 236 + 64 + k) * 9 + t);
    } else {
        int kf = (s - 6) * 32 + klocal;
        v = ldv(src + ((size_t)co * 236 + kf) * 9 + t);
    }
    dst[(((size_t)(t * 8 + s) * NTtot + ubase + u) * 64 + lane) * 8 + j] = f2b(v);
}

// trunk weights [48][CIN][3][3] -> frag order, Kpad=64 (2 ksteps), NT=3
template<typename IT>
__global__ __launch_bounds__(256) void wfrag_trunk(const int* __restrict__ flag,
                                                   const IT* __restrict__ src,
                                                   bf16* __restrict__ dst, int CIN)
{
    if (gate_skip<IT>(flag)) return;
    int i = blockIdx.x * 256 + threadIdx.x;
    if (i >= 9*2*3*64*8) return;
    int j    = i & 7;
    int lane = (i >> 3) & 63;
    int rest = i >> 9;
    int u = rest % 3; rest /= 3;
    int s = rest & 1;
    int t = rest >> 1;
    int k = s * 32 + ((lane >> 4) << 3) + j;
    int co = u * 16 + (lane & 15);
    float v = (k < CIN) ? ldv(src + ((size_t)co * CIN + k) * 9 + t) : 0.f;
    dst[i] = f2b(v);
}

// small params: 0:zb 64:rb 128:qb 192:g1s 240:g1b 288:g2s 336:g2b
// 384:wd 432:wx 480:wy 528:wc 576:bd 577:bx 578:by 579:bc
template<typename IT>
__global__ void cvt_small(const int* __restrict__ flag,
    const IT* zb, const IT* rb, const IT* qb,
    const IT* g1s, const IT* g1b, const IT* g2s, const IT* g2b,
    const IT* wd, const IT* wx, const IT* wy, const IT* wc,
    const IT* bd, const IT* bx, const IT* by, const IT* bc,
    bf16* __restrict__ dst)
{
    if (gate_skip<IT>(flag)) return;
    int i = blockIdx.x * 256 + threadIdx.x;
    if (i >= 580) return;
    const IT* src; int off;
    if      (i < 64)  { src = zb;  off = i; }
    else if (i < 128) { src = rb;  off = i - 64; }
    else if (i < 192) { src = qb;  off = i - 128; }
    else if (i < 240) { src = g1s; off = i - 192; }
    else if (i < 288) { src = g1b; off = i - 240; }
    else if (i < 336) { src = g2s; off = i - 288; }
    else if (i < 384) { src = g2b; off = i - 336; }
    else if (i < 432) { src = wd;  off = i - 384; }
    else if (i < 480) { src = wx;  off = i - 432; }
    else if (i < 528) { src = wy;  off = i - 480; }
    else if (i < 576) { src = wc;  off = i - 528; }
    else if (i == 576){ src = bd;  off = 0; }
    else if (i == 577){ src = bx;  off = 0; }
    else if (i == 578){ src = by;  off = 0; }
    else              { src = bc;  off = 0; }
    dst[i] = f2b(ldv(src + off));
}

// ------------------------------------------------------------------- ctx -----
// 4 threads per pixel (thread = pixel x group-pair). Writes xin record
// [B][RH][RW][256]: 0..63 fL, 64..127 fR_w, 128 d,129 sx,130 sy,131 conf,
// 132..171 cost, 172..191 zero, 192..255 feat.
template<typename IT>
__global__ __launch_bounds__(256) void build_ctx_nhwc(
    const int* __restrict__ flag,
    const IT* __restrict__ d_, const IT* __restrict__ sx_,
    const IT* __restrict__ sy_, const IT* __restrict__ conf_,
    const IT* __restrict__ fL, const IT* __restrict__ fR,
    const IT* __restrict__ feat,
    bf16* __restrict__ xin, float* __restrict__ dscf)
{
    if (gate_skip<IT>(flag)) return;
    const int lane = threadIdx.x & 63;
    const int g2   = threadIdx.x >> 6;            // 0..3: channels 16*g2..+15
    const int blk  = blockIdx.x;
    const int x    = ((blk & 3) << 6) | lane;
    const int y    = (blk >> 2) & (H_ - 1);
    const int b    = blk >> 9;
    const int pix  = (b << 15) | (y << 8) | x;

    const float d0   = ldv(d_ + pix);
    const float tpos = (float)x - d0;
    const float xw   = fminf(fmaxf(tpos, 0.f), 255.f);
    const float x0f  = floorf(xw);
    const float w1   = xw - x0f;
    const int   i0   = (int)x0f;
    const int   i1   = min(i0 + 1, W_ - 1);
    const bool  safe = (tpos >= 2.f) && (tpos < 253.f);
    const int   jb   = i0 - 2;                    // valid only when safe

    int   j0[5], j1[5];
    float wq[5];
#pragma unroll
    for (int dd = 0; dd < 5; ++dd) {
        float cd = fminf(fmaxf(tpos - (float)(dd - 2), 0.f), 255.f);
        float c0 = floorf(cd);
        wq[dd] = cd - c0;
        j0[dd] = (int)c0;
        j1[dd] = min(j0[dd] + 1, W_ - 1);
    }

    bf16* rec = xin + ((size_t)(b * RH + y + 1) * RW + 1 + x) * 256;
    const IT* fLr = fL   + (size_t)(b * 64 + (g2 << 4)) * HW_ + y * W_;
    const IT* fRr = fR   + (size_t)(b * 64 + (g2 << 4)) * HW_ + y * W_;
    const IT* fTr = feat + (size_t)(b * 64 + (g2 << 4)) * HW_ + y * W_;

    float cost[10];
#pragma unroll
    for (int k = 0; k < 10; ++k) cost[k] = 0.f;

    unsigned short bL[8], bW[8], bF[8];
#pragma unroll
    for (int cc = 0; cc < 16; ++cc) {
        const IT* fr = fRr + (size_t)cc * HW_;
        float fl = ldv(fLr + (size_t)cc * HW_ + x);
        float ft = ldv(fTr + (size_t)cc * HW_ + x);
        float fw, s0, s1, s3, s4;
        if (safe) {
            float v0 = ldv(fr + jb),     v1 = ldv(fr + jb + 1);
            float v2 = ldv(fr + jb + 2), v3 = ldv(fr + jb + 3);
            float v4 = ldv(fr + jb + 4), v5 = ldv(fr + jb + 5);
            float a = 1.f - w1;
            fw = v2 * a + v3 * w1;
            s0 = v4 * a + v5 * w1;
            s1 = v3 * a + v4 * w1;
            s3 = v1 * a + v2 * w1;
            s4 = v0 * a + v1 * w1;
        } else {
            fw = ldv(fr + i0) * (1.f - w1) + ldv(fr + i1) * w1;
            s0 = ldv(fr + j0[0]) * (1.f - wq[0]) + ldv(fr + j1[0]) * wq[0];
            s1 = ldv(fr + j0[1]) * (1.f - wq[1]) + ldv(fr + j1[1]) * wq[1];
            s3 = ldv(fr + j0[3]) * (1.f - wq[3]) + ldv(fr + j1[3]) * wq[3];
            s4 = ldv(fr + j0[4]) * (1.f - wq[4]) + ldv(fr + j1[4]) * wq[4];
        }
        const int gg = cc >> 3;
        cost[gg * 5 + 0] = fmaf(fl, s0, cost[gg * 5 + 0]);
        cost[gg * 5 + 1] = fmaf(fl, s1, cost[gg * 5 + 1]);
        cost[gg * 5 + 2] = fmaf(fl, fw, cost[gg * 5 + 2]);   // dd=2 sample == fR_w
        cost[gg * 5 + 3] = fmaf(fl, s3, cost[gg * 5 + 3]);
        cost[gg * 5 + 4] = fmaf(fl, s4, cost[gg * 5 + 4]);
        bL[cc & 7] = f2bu(fl);
        bW[cc & 7] = f2bu(fw);
        bF[cc & 7] = f2bu(ft);
        if ((cc & 7) == 7) {
            const int c0i = (g2 << 4) + cc - 7;
            *(uint4*)(rec + c0i)       = *(uint4*)bL;
            *(uint4*)(rec + 64 + c0i)  = *(uint4*)bW;
            *(uint4*)(rec + 192 + c0i) = *(uint4*)bF;
        }
    }

    bf16* cst = rec + 132 + g2 * 10;
#pragma unroll
    for (int k = 0; k < 5; ++k) {
        unsigned int pk = (unsigned int)f2bu(cost[2 * k] * 0.125f) |
                          ((unsigned int)f2bu(cost[2 * k + 1] * 0.125f) << 16);
        *(unsigned int*)(cst + 2 * k) = pk;
    }

    if (g2 == 0) {
        float sxv = ldv(sx_ + pix);
        float syv = ldv(sy_ + pix);
        float cfv = ldv(conf_ + pix);
        *(unsigned int*)(rec + 128) = (unsigned int)f2bu(d0)  | ((unsigned int)f2bu(sxv) << 16);
        *(unsigned int*)(rec + 130) = (unsigned int)f2bu(syv) | ((unsigned int)f2bu(cfv) << 16);
        dscf[pix]            = d0;
        dscf[NPIX + pix]     = sxv;
        dscf[2 * NPIX + pix] = syv;
        dscf[3 * NPIX + pix] = cfv;
    } else if (g2 == 3) {
#pragma unroll
        for (int k = 0; k < 10; ++k)
            *(unsigned int*)(rec + 172 + 2 * k) = 0u;
    }
}

// ----------------------------------------------------------------- zeroing ---
__global__ __launch_bounds__(256) void zero_halo(bf16* __restrict__ buf, int CP)
{
    int yy = blockIdx.x % RH;
    int b  = blockIdx.x / RH;
    for (int x = threadIdx.x; x < RW; x += 256) {
        bool h = (yy == 0) | (yy == RH - 1) | (x == 0) | (x == RW - 1);
        if (!h) continue;
        bf16* p = buf + ((size_t)(b * RH + yy) * RW + x) * CP;
        uint4 z = {0u, 0u, 0u, 0u};
        for (int c = 0; c < CP; c += 8)
            *(uint4*)(p + c) = z;
    }
}

__global__ __launch_bounds__(256) void zero_full(bf16* __restrict__ buf, int n16)
{
    int i = blockIdx.x * 256 + threadIdx.x;
    if (i >= n16) return;
    uint4 z = {0u, 0u, 0u, 0u};
    *(uint4*)(buf + (size_t)i * 8) = z;
}

// -------------------------------------------------- LDS-tiled MFMA 3x3 conv --
// Block = 64x4 output tile (4 waves). 64-ch chunks staged in LDS (XOR-swizzled
// 16B units). NCH: chunks (4 = GRU 256ch, 1 = trunk 64ch).
// MODE 4: fused z+r (NT=8): u<4 sigmoid->outn(xz); u>=4 sigmoid*feat->o2(xr)
// MODE 1: GRU combine -> outn(xt) + d_out slot3; chunk 3 staged from srcB (xr)
// MODE 2: plain -> outn (trunk)
template<int NCH, int NT, int MODE>
__global__ __launch_bounds__(256) void conv_tile(
    const bf16* __restrict__ srcA, const bf16* __restrict__ srcB,
    const bf16* __restrict__ wfrag, const bf16* __restrict__ bias,
    bf16* __restrict__ outn, int CPO,
    bf16* __restrict__ o2,
    void* __restrict__ dout, const int* __restrict__ flag)
{
    constexpr int CPA = (NCH == 4) ? 256 : 64;
    __shared__ uint4 lds4[6 * 66 * 8];          // 50688 B

    const int tid  = threadIdx.x;
    const int lane = tid & 63;
    const int wv   = tid >> 6;
    const int m    = lane & 15;
    const int quad = lane >> 4;

    const int bx = blockIdx.x;
    const int x0 = (bx & 3) << 6;
    const int y0 = ((bx >> 2) & 31) << 2;
    const int b  = bx >> 7;

    f32x4 acc[4][NT];
#pragma unroll
    for (int mt = 0; mt < 4; ++mt)
#pragma unroll
        for (int u = 0; u < NT; ++u)
            acc[mt][u] = (f32x4){0.f, 0.f, 0.f, 0.f};

    const size_t tileBase = (size_t)(b * RH + y0) * RW + x0;

    for (int ch = 0; ch < NCH; ++ch) {
        if (ch) __syncthreads();
        const bool useB = (MODE == 1) && (ch == 3);
        const bf16* gsrc = useB ? srcB : srcA;
        const int cpg  = useB ? 64 : CPA;
        const int cofs = useB ? 0 : ch * 64;
        for (int idx = tid; idx < 3168; idx += 256) {
            const int part = idx & 7;
            const int rp   = idx >> 3;
            const int rr   = rp / 66;
            const int cc   = rp - rr * 66;
            const uint4 v = *(const uint4*)(gsrc +
                (tileBase + (size_t)rr * RW + cc) * cpg + cofs + part * 8);
            lds4[rp * 8 + (part ^ (cc & 7))] = v;
        }
        __syncthreads();
#pragma unroll
        for (int t = 0; t < 9; ++t) {
            const int dy = t / 3, dx = t % 3;
#pragma unroll
            for (int s = 0; s < 2; ++s) {
                bf16x8 a[4];
#pragma unroll
                for (int mt = 0; mt < 4; ++mt) {
                    const int cc = mt * 16 + m + dx;
                    const int j  = (s * 4 + quad) ^ (cc & 7);
                    a[mt] = ((const bf16x8*)lds4)[((wv + dy) * 66 + cc) * 8 + j];
                }
#pragma unroll
                for (int u = 0; u < NT; ++u) {
                    bf16x8 bw = *(const bf16x8*)(wfrag +
                        ((size_t)(((t * (NCH * 2) + ch * 2 + s) * NT + u) * 64 + lane) << 3));
#pragma unroll
                    for (int mt = 0; mt < 4; ++mt)
                        acc[mt][u] = __builtin_amdgcn_mfma_f32_16x16x32_bf16(
                            a[mt], bw, acc[mt][u], 0, 0, 0);
                }
            }
        }
    }

    const int gy = y0 + wv;
    const size_t rec0 = (size_t)(b * RH + gy + 1) * RW + 1 + x0;
#pragma unroll
    for (int mt = 0; mt < 4; ++mt) {
        const int px0 = mt * 16 + quad * 4;
#pragma unroll
        for (int u = 0; u < NT; ++u) {
            if (MODE == 4) {
                const int n = (u & 3) * 16 + m;
                float bn = b2f(bias[(u < 4 ? 0 : 64) + n]);
#pragma unroll
                for (int r = 0; r < 4; ++r) {
                    float v = acc[mt][u][r] + bn;
                    float sg = 1.f / (1.f + expf(-v));
                    if (u < 4) {
                        outn[(rec0 + px0 + r) * 64 + n] = f2b(sg);
                    } else {
                        float fv = b2f(srcA[(rec0 + px0 + r) * 256 + 192 + n]);
                        o2[(rec0 + px0 + r) * 64 + n] = f2b(sg * fv);
                    }
                }
            } else if (MODE == 2) {
                const int n = u * 16 + m;
#pragma unroll
                for (int r = 0; r < 4; ++r)
                    outn[(rec0 + px0 + r) * CPO + n] = f2b(acc[mt][u][r]);
            } else if (MODE == 1) {
                const int n = u * 16 + m;
                float bn = b2f(bias[n]);
                float hv[4];
#pragma unroll
                for (int r = 0; r < 4; ++r) {
                    float q = tanhf(acc[mt][u][r] + bn);
                    size_t ai = (rec0 + px0 + r) * 64 + n;
                    float zv = b2f(o2[ai]);                       // xz
                    float fv = b2f(srcA[(rec0 + px0 + r) * 256 + 192 + n]);
                    hv[r] = (1.f - zv) * fv + zv * q;
                    outn[ai] = f2b(hv[r]);
                }
                size_t pb = ((size_t)(b * 64 + n) << 15) + gy * W_ + x0 + px0;
                if (*flag) {
                    float4 o; o.x = hv[0]; o.y = hv[1]; o.z = hv[2]; o.w = hv[3];
                    *(float4*)((float*)dout + 393216 + pb) = o;
                } else {
                    ushort4 o;
                    o.x = f2bu(hv[0]); o.y = f2bu(hv[1]);
                    o.z = f2bu(hv[2]); o.w = f2bu(hv[3]);
                    *(ushort4*)((bf16*)dout + 393216 + pb) = o;
                }
            }
        }
    }
}

// -------------------------------------------------------------- groupnorm ----
__global__ __launch_bounds__(256) void gn_reduce_nhwc(const bf16* __restrict__ buf,
                                                      float* __restrict__ part, int CP)
{
    const int gp = blockIdx.x >> 3;     // b*8+g
    const int pt = blockIdx.x & 7;
    const int b = gp >> 3, g = gp & 7;
    const int lo = pt * 4193;
    const int hi = min(lo + 4193, IPX);
    const bf16* base = buf + (size_t)b * IPX * CP + g * 6;
    float s = 0.f, ss = 0.f;
    for (int px = lo + threadIdx.x; px < hi; px += 256) {
        const bf16* q = base + (size_t)px * CP;
#pragma unroll
        for (int c = 0; c < 6; ++c) {
            float v = b2f(q[c]);
            s += v;
            ss = fmaf(v, v, ss);
        }
    }
#pragma unroll
    for (int o = 32; o > 0; o >>= 1) {
        s  += __shfl_down(s, o, 64);
        ss += __shfl_down(ss, o, 64);
    }
    __shared__ float sm[8];
    int wid = threadIdx.x >> 6;
    if ((threadIdx.x & 63) == 0) { sm[wid * 2] = s; sm[wid * 2 + 1] = ss; }
    __syncthreads();
    if (threadIdx.x == 0) {
        float S = 0.f, SS = 0.f;
        for (int i = 0; i < 4; ++i) { S += sm[i * 2]; SS += sm[i * 2 + 1]; }
        part[(gp * 8 + pt) * 2]     = S;
        part[(gp * 8 + pt) * 2 + 1] = SS;
    }
}

__global__ void gn_finalize(const float* __restrict__ part, float* __restrict__ stats)
{
    int gp = threadIdx.x;
    if (gp >= 32) return;
    float S = 0.f, SS = 0.f;
    for (int i = 0; i < 8; ++i) {
        S  += part[(gp * 8 + i) * 2];
        SS += part[(gp * 8 + i) * 2 + 1];
    }
    const float N = 6.f * HW_;
    float mn  = S / N;
    float var = SS / N - mn * mn;
    var = fmaxf(var, 0.f);
    stats[gp * 2]     = mn;
    stats[gp * 2 + 1] = rsqrtf(var + 1e-5f);
}

__global__ __launch_bounds__(256) void gn_apply_nhwc(bf16* __restrict__ buf,
                                                     const float* __restrict__ stats,
                                                     const bf16* __restrict__ scbi,
                                                     int CP)
{
    const int y = blockIdx.x & (H_ - 1);
    const int b = blockIdx.x >> 7;
    bf16* base = buf + ((size_t)(b * RH + y + 1) * RW + 1) * CP;
    for (int j = threadIdx.x; j < W_ * 48; j += 256) {
        int px = j / 48;
        int c  = j - px * 48;
        int g  = c / 6;
        float mn = stats[(b * 8 + g) * 2], rr = stats[(b * 8 + g) * 2 + 1];
        size_t idx = (size_t)px * CP + c;
        float v = (b2f(base[idx]) - mn) * rr * b2f(scbi[c]) + b2f(scbi[48 + c]);
        base[idx] = f2b(v / (1.f + expf(-v)));
    }
}

// ------------------------------------------------------------------ heads ----
__global__ __launch_bounds__(256) void heads_k(
    const bf16* __restrict__ xt2,      // NHWC stride 48
    const bf16* __restrict__ sp,
    const float* __restrict__ dscf,
    void* __restrict__ out_base,
    const int* __restrict__ flag)
{
    const int x = threadIdx.x;
    const int y = blockIdx.x & (H_ - 1);
    const int b = blockIdx.x >> 7;
    const int pix = (b << 15) | (y << 8) | x;
    const bf16* t = xt2 + ((size_t)(b * RH + y + 1) * RW + 1 + x) * 48;
    float ad = 0.f, ax = 0.f, ay = 0.f, ac = 0.f;
#pragma unroll
    for (int c = 0; c < 48; ++c) {
        float v = b2f(t[c]);
        ad = fmaf(v, b2f(sp[384 + c]), ad);
        ax = fmaf(v, b2f(sp[432 + c]), ax);
        ay = fmaf(v, b2f(sp[480 + c]), ay);
        ac = fmaf(v, b2f(sp[528 + c]), ac);
    }
    float dv  = dscf[pix];
    float sxv = dscf[NPIX + pix];
    float syv = dscf[2 * NPIX + pix];
    float cfv = dscf[3 * NPIX + pix];

    float dval = ad + b2f(sp[576]) + dv;
    float spv = fmaxf(dval, 0.f) + log1pf(expf(-fabsf(dval)));
    float sxo = sxv + 0.1f * (ax + b2f(sp[577]));
    float syo = syv + 0.1f * (ay + b2f(sp[578]));
    float cvv = 1.f / (1.f + expf(-(ac + b2f(sp[579]) + 2.f * cfv - 1.f)));

    if (*flag) {
        float* of = (float*)out_base;
        of[pix]            = spv;
        of[NPIX + pix]     = sxo;
        of[2 * NPIX + pix] = syo;
        of[8781824 + pix]  = cvv;
    } else {
        bf16* ob = (bf16*)out_base;
        ob[pix]            = f2b(spv);
        ob[NPIX + pix]     = f2b(sxo);
        ob[2 * NPIX + pix] = f2b(syo);
        ob[8781824 + pix]  = f2b(cvv);
    }
}

// ------------------------------------------------------------------ launch ---
extern "C" void kernel_launch(void* const* d_in, const int* in_sizes, int n_in,
                              void* d_out, int out_size, void* d_ws, size_t ws_size,
                              hipStream_t stream)
{
    char* ws = (char*)d_ws;
    size_t off = 0;
    bf16* xin = (bf16*)(ws + off); off += (size_t)B_ * IPX * 256 * 2;   // 68.7 MB
    bf16* xz  = (bf16*)(ws + off); off += (size_t)B_ * IPX * 64 * 2;    // 17.2 MB (later xt1)
    bf16* xr  = (bf16*)(ws + off); off += (size_t)B_ * IPX * 64 * 2;    // 17.2 MB (later xt2)
    bf16* xt  = (bf16*)(ws + off); off += (size_t)B_ * IPX * 64 * 2;    // 17.2 MB (h_new)
    bf16* xt1 = xz;
    bf16* xt2 = xr;
    float* dscf = (float*)(ws + off); off += (size_t)4 * NPIX * 4;      // 2.1 MB
    bf16* wfzr = (bf16*)(ws + off); off += (size_t)9*8*8*64*8 * 2;      // z||r, NT=8
    bf16* wfq  = (bf16*)(ws + off); off += (size_t)9*8*4*64*8 * 2;
    bf16* wf1  = (bf16*)(ws + off); off += (size_t)9*2*3*64*8 * 2;
    bf16* wf2  = (bf16*)(ws + off); off += (size_t)9*2*3*64*8 * 2;
    bf16*  sprm  = (bf16*)(ws + off); off += 1536;
    float* gpart = (float*)(ws + off); off += 512 * 4;
    float* gstat = (float*)(ws + off); off += 64 * 4;
    int*   flag  = (int*)(ws + off);   off += 256;

    detect_k<<<1, 64, 0, stream>>>((const unsigned int*)d_in[4], flag);

    // ---- weight/param staging (dual dtype; mismatched variant early-outs) ----
    wfrag_gru<bf16 ><<<576, 256, 0, stream>>>(flag, (const bf16*)d_in[7],  wfzr, 8, 0);
    wfrag_gru<float><<<576, 256, 0, stream>>>(flag, (const float*)d_in[7], wfzr, 8, 0);
    wfrag_gru<bf16 ><<<576, 256, 0, stream>>>(flag, (const bf16*)d_in[9],  wfzr, 8, 4);
    wfrag_gru<float><<<576, 256, 0, stream>>>(flag, (const float*)d_in[9], wfzr, 8, 4);
    wfrag_gru<bf16 ><<<576, 256, 0, stream>>>(flag, (const bf16*)d_in[11],  wfq, 4, 0);
    wfrag_gru<float><<<576, 256, 0, stream>>>(flag, (const float*)d_in[11], wfq, 4, 0);
    wfrag_trunk<bf16 ><<<108, 256, 0, stream>>>(flag, (const bf16*)d_in[13],  wf1, 64);
    wfrag_trunk<float><<<108, 256, 0, stream>>>(flag, (const float*)d_in[13], wf1, 64);
    wfrag_trunk<bf16 ><<<108, 256, 0, stream>>>(flag, (const bf16*)d_in[16],  wf2, 48);
    wfrag_trunk<float><<<108, 256, 0, stream>>>(flag, (const float*)d_in[16], wf2, 48);
    cvt_small<bf16><<<3, 256, 0, stream>>>(flag,
        (const bf16*)d_in[8], (const bf16*)d_in[10], (const bf16*)d_in[12],
        (const bf16*)d_in[14], (const bf16*)d_in[15], (const bf16*)d_in[17], (const bf16*)d_in[18],
        (const bf16*)d_in[19], (const bf16*)d_in[21], (const bf16*)d_in[23], (const bf16*)d_in[25],
        (const bf16*)d_in[20], (const bf16*)d_in[22], (const bf16*)d_in[24], (const bf16*)d_in[26],
        sprm);
    cvt_small<float><<<3, 256, 0, stream>>>(flag,
        (const float*)d_in[8], (const float*)d_in[10], (const float*)d_in[12],
        (const float*)d_in[14], (const float*)d_in[15], (const float*)d_in[17], (const float*)d_in[18],
        (const float*)d_in[19], (const float*)d_in[21], (const float*)d_in[23], (const float*)d_in[25],
        (const float*)d_in[20], (const float*)d_in[22], (const float*)d_in[24], (const float*)d_in[26],
        sprm);

    // ---- halo zero + fused ctx/feat NHWC staging ----
    zero_halo<<<B_ * RH, 256, 0, stream>>>(xin, 256);
    zero_halo<<<B_ * RH, 256, 0, stream>>>(xr, 64);
    zero_halo<<<B_ * RH, 256, 0, stream>>>(xt, 64);
    build_ctx_nhwc<bf16 ><<<B_ * H_ * 4, 256, 0, stream>>>(flag,
        (const bf16*)d_in[0], (const bf16*)d_in[1], (const bf16*)d_in[2],
        (const bf16*)d_in[3], (const bf16*)d_in[5], (const bf16*)d_in[6],
        (const bf16*)d_in[4], xin, dscf);
    build_ctx_nhwc<float><<<B_ * H_ * 4, 256, 0, stream>>>(flag,
        (const float*)d_in[0], (const float*)d_in[1], (const float*)d_in[2],
        (const float*)d_in[3], (const float*)d_in[5], (const float*)d_in[6],
        (const float*)d_in[4], xin, dscf);

    // ---- GRU convs: fused z+r, then q ----
    conv_tile<4, 8, 4><<<512, 256, 0, stream>>>(xin, nullptr, wfzr, sprm,
        xz, 64, xr, nullptr, flag);
    conv_tile<4, 4, 1><<<512, 256, 0, stream>>>(xin, xr, wfq, sprm + 128,
        xt, 64, xz, d_out, flag);

    // ---- trunk ----
    zero_full<<<(B_ * IPX * 64 / 8 + 255) / 256, 256, 0, stream>>>(xt1, B_ * IPX * 64 / 8);
    zero_halo<<<B_ * RH, 256, 0, stream>>>(xt2, 48);
    conv_tile<1, 3, 2><<<512, 256, 0, stream>>>(xt, nullptr, wf1, sprm,
        xt1, 64, nullptr, nullptr, flag);
    gn_reduce_nhwc<<<256, 256, 0, stream>>>(xt1, gpart, 64);
    gn_finalize<<<1, 32, 0, stream>>>(gpart, gstat);
    gn_apply_nhwc<<<B_ * H_, 256, 0, stream>>>(xt1, gstat, sprm + 192, 64);

    conv_tile<1, 3, 2><<<512, 256, 0, stream>>>(xt1, nullptr, wf2, sprm,
        xt2, 48, nullptr, nullptr, flag);
    gn_reduce_nhwc<<<256, 256, 0, stream>>>(xt2, gpart, 48);
    gn_finalize<<<1, 32, 0, stream>>>(gpart, gstat);
    gn_apply_nhwc<<<B_ * H_, 256, 0, stream>>>(xt2, gstat, sprm + 288, 48);

    heads_k<<<B_ * H_, 256, 0, stream>>>(xt2, sprm, dscf, d_out, flag);
}